// Round 3
// baseline (437.464 us; speedup 1.0000x reference)
//
#include <hip/hip_runtime.h>

// shuffleAug: the 5 chained per-sample gathers compose to one affine map
//   out[b,c,i,j] = in[b,c, sA*p+tA, sC*q+tC], (p,q) = swap ? (j,i) : (i,j)
// with (s,t) in {(1,0),(-1,127)}. One block per 128x128 plane:
//  - global loads/stores perfectly linear (1KB/wave) for ALL flip combos
//  - transpose handled in 64KB swizzled LDS (swap blocks only)
//  - non-swap blocks: direct streaming copy, no LDS, no barrier

#define HWDIM  128
#define BCNT   32
#define CHALF  64
#define NF4    (HWDIM * HWDIM / 4)   // 4096 float4 slots per plane
#define PASSES (NF4 / 256)           // 16 float4 per thread

__global__ __launch_bounds__(256, 2) void shuffle_aug_kernel(
    const float* __restrict__ x1,
    const float* __restrict__ x2,
    const int*   __restrict__ flips,   // (5, 32) int32
    float*       __restrict__ out)
{
    // slot(r,c4) = (r<<5) | (c4 ^ ((r>>2)&31)) : b128 writes 2-way max,
    // swap-case stride-4-row column reads 4-way max.
    __shared__ float4 lds4[NF4];       // 64 KiB -> 2 blocks/CU

    const int bid = blockIdx.x;
    const int ct  = bid & 127;         // concatenated channel
    const int b   = bid >> 7;          // sample

    const int f0 = flips[0 * BCNT + b];
    const int f1 = flips[1 * BCNT + b];
    const int f2 = flips[2 * BCNT + b];   // swap
    const int f3 = flips[3 * BCNT + b];
    const int f4 = flips[4 * BCNT + b];

    // compose: step4 flipX(i), step5 flipY(j); then swap; then step2, step1
    int sI = f3 ? -1 : 1, tI = f3 ? 127 : 0;
    int sJ = f4 ? -1 : 1, tJ = f4 ? 127 : 0;
    int sA, tA, sC, tC;
    if (f2) {
        sA = f0 ? -sJ : sJ;  tA = f0 ? 127 - tJ : tJ;   // a = sA*j + tA
        sC = f1 ? -sI : sI;  tC = f1 ? 127 - tI : tI;   // c = sC*i + tC
    } else {
        sA = f0 ? -sI : sI;  tA = f0 ? 127 - tI : tI;   // a = sA*i + tA
        sC = f1 ? -sJ : sJ;  tC = f1 ? 127 - tJ : tJ;   // c = sC*j + tC
    }

    const int cLoc = ct & (CHALF - 1);
    const size_t plane = (size_t)(b * CHALF + cLoc) * (HWDIM * HWDIM);
    const float4* __restrict__ src4 =
        reinterpret_cast<const float4*>(((ct < CHALF) ? x1 : x2) + plane);
    float4* __restrict__ dst4 = reinterpret_cast<float4*>(
        out + ((ct < CHALF) ? (size_t)0 : (size_t)BCNT * CHALF * HWDIM * HWDIM) + plane);

    const int t = threadIdx.x;
    const bool revA = ((f2 ? (f0 ^ f4) : (f0 ^ f3)) != 0);  // sA < 0
    const bool revC = ((f2 ? (f1 ^ f3) : (f1 ^ f4)) != 0);  // sC < 0
    (void)sA; (void)tA; (void)sC; (void)tC;

    if (!f2) {
        // ---- direct streaming path (no LDS, no barrier) ----
#pragma unroll
        for (int p = 0; p < PASSES; ++p) {
            const int d   = p * 256 + t;
            const int i   = d >> 5, jf4 = d & 31;
            const int a   = revA ? (127 - i)  : i;
            const int cf4 = revC ? (31 - jf4) : jf4;
            float4 v = src4[(a << 5) | cf4];
            if (revC) { float x = v.x; v.x = v.w; v.w = x;
                        float y = v.y; v.y = v.z; v.z = y; }
            dst4[d] = v;
        }
    } else {
        // ---- transpose path through swizzled LDS ----
        float4 stage[PASSES];
#pragma unroll
        for (int p = 0; p < PASSES; ++p) stage[p] = src4[p * 256 + t];
#pragma unroll
        for (int p = 0; p < PASSES; ++p) {
            const int d = p * 256 + t;
            const int r = d >> 5, c4 = d & 31;
            lds4[(r << 5) | (c4 ^ ((r >> 2) & 31))] = stage[p];
        }
        __syncthreads();

        const float* __restrict__ ldsf = reinterpret_cast<const float*>(lds4);
#pragma unroll
        for (int p = 0; p < PASSES; ++p) {
            const int d = p * 256 + t;
            const int i = d >> 5, jf4 = d & 31;
            const int c  = revC ? (127 - i) : i;    // c = sC*i + tC (fixed per thread)
            const int ch = c >> 2, ce = c & 3;
            float ov[4];
#pragma unroll
            for (int e = 0; e < 4; ++e) {
                const int j = 4 * jf4 + e;
                const int a = revA ? (127 - j) : j; // a = sA*j + tA
                ov[e] = ldsf[(((a << 5) | (ch ^ ((a >> 2) & 31))) << 2) + ce];
            }
            dst4[d] = make_float4(ov[0], ov[1], ov[2], ov[3]);
        }
    }
}

extern "C" void kernel_launch(void* const* d_in, const int* in_sizes, int n_in,
                              void* d_out, int out_size, void* d_ws, size_t ws_size,
                              hipStream_t stream) {
    const float* x1    = (const float*)d_in[0];
    const float* x2    = (const float*)d_in[1];
    const int*   flips = (const int*)d_in[2];
    float*       out   = (float*)d_out;

    const int grid = BCNT * 2 * CHALF;   // 32 * 128 = 4096 planes
    shuffle_aug_kernel<<<grid, 256, 0, stream>>>(x1, x2, flips, out);
}

// Round 4
// 434.097 us; speedup vs baseline: 1.0078x; 1.0078x over previous
//
#include <hip/hip_runtime.h>

// shuffleAug: 5 chained per-sample gathers compose to one affine map
//   out[i][j] = in[rA(i)][rC(j)]            (no swap)
//   out[i][j] = in[rA(j)][rC(i)]            (swap)
// where rA/rC are identity or (127 - idx), derived from the 5 flip bits.
// One 64x64 output tile per block (grid 16384, 256 thr):
//  - LDS 64x65 floats (16.6 KiB) -> 8 blocks/CU -> FULL 32-wave occupancy
//  - non-swap blocks: direct streaming copy, no LDS, no barrier
//  - swap blocks: coalesced load -> padded-LDS transpose -> coalesced store
//  - all global access: 4x256B dense segments per wave instruction

#define HWDIM  128
#define BCNT   32
#define CHALF  64
#define TILE   64

__global__ __launch_bounds__(256) void shuffle_aug_kernel(
    const float* __restrict__ x1,
    const float* __restrict__ x2,
    const int*   __restrict__ flips,   // (5, 32) int32
    float*       __restrict__ out)
{
    __shared__ float lds[TILE][TILE + 1];   // +1 pad: column reads conflict-light

    const int bid  = blockIdx.x;
    const int tile = bid & 3;              // 2x2 tiles of the plane
    const int ct   = (bid >> 2) & 127;     // concatenated channel
    const int b    = bid >> 9;             // sample

    const int f0 = flips[0 * BCNT + b];
    const int f1 = flips[1 * BCNT + b];
    const int f2 = flips[2 * BCNT + b];    // swap
    const int f3 = flips[3 * BCNT + b];
    const int f4 = flips[4 * BCNT + b];

    const bool swp  = (f2 != 0);
    const bool revA = ((swp ? (f0 ^ f4) : (f0 ^ f3)) != 0);  // row-source reversed
    const bool revC = ((swp ? (f1 ^ f3) : (f1 ^ f4)) != 0);  // col-source reversed

    const int i0 = (tile >> 1) * TILE;     // output tile origin
    const int j0 = (tile & 1) * TILE;

    const int cLoc = ct & (CHALF - 1);
    const size_t plane = (size_t)(b * CHALF + cLoc) * (HWDIM * HWDIM);
    const float4* __restrict__ src4 =
        reinterpret_cast<const float4*>(((ct < CHALF) ? x1 : x2) + plane);
    float4* __restrict__ dst4 = reinterpret_cast<float4*>(
        out + ((ct < CHALF) ? (size_t)0 : (size_t)BCNT * CHALF * HWDIM * HWDIM) + plane);

    const int t = threadIdx.x;

    if (!swp) {
        // ---- direct copy: out[i][j] = in[rA(i)][rC(j)] ----
#pragma unroll
        for (int p = 0; p < 4; ++p) {
            const int d   = p * 256 + t;
            const int ir  = d >> 4;                 // 0..63 tile row
            const int jf4 = d & 15;                 // 0..15 tile f4-col
            const int i   = i0 + ir;
            const int a   = revA ? 127 - i : i;
            const int cf4 = revC ? (31 - (j0 >> 2) - jf4) : ((j0 >> 2) + jf4);
            float4 v = src4[a * 32 + cf4];
            if (revC) { float x = v.x; v.x = v.w; v.w = x;
                        float y = v.y; v.y = v.z; v.z = y; }
            dst4[i * 32 + (j0 >> 2) + jf4] = v;
        }
    } else {
        // ---- transpose: out[i][j] = in[rA(j)][rC(i)] ----
        // source rows a = rA(j), j in [j0,j0+64)  -> [aMin, aMin+64)
        // source cols c = rC(i), i in [i0,i0+64)  -> [cMin, cMin+64)
        const int aMin = revA ? (TILE - j0) : j0;
        const int cMin = revC ? (TILE - i0) : i0;

#pragma unroll
        for (int p = 0; p < 4; ++p) {
            const int d  = p * 256 + t;
            const int r  = d >> 4;                  // 0..63 source row offset
            const int c4 = d & 15;                  // 0..15 source f4-col
            float4 v = src4[(aMin + r) * 32 + (cMin >> 2) + c4];
            lds[r][c4 * 4 + 0] = v.x;
            lds[r][c4 * 4 + 1] = v.y;
            lds[r][c4 * 4 + 2] = v.z;
            lds[r][c4 * 4 + 3] = v.w;
        }
        __syncthreads();

#pragma unroll
        for (int p = 0; p < 4; ++p) {
            const int d   = p * 256 + t;
            const int ir  = d >> 4;
            const int jf4 = d & 15;
            const int i   = i0 + ir;
            const int c   = (revC ? 127 - i : i) - cMin;
            float ov[4];
#pragma unroll
            for (int e = 0; e < 4; ++e) {
                const int j = j0 + 4 * jf4 + e;
                const int a = (revA ? 127 - j : j) - aMin;
                ov[e] = lds[a][c];
            }
            dst4[i * 32 + (j0 >> 2) + jf4] = make_float4(ov[0], ov[1], ov[2], ov[3]);
        }
    }
}

extern "C" void kernel_launch(void* const* d_in, const int* in_sizes, int n_in,
                              void* d_out, int out_size, void* d_ws, size_t ws_size,
                              hipStream_t stream) {
    const float* x1    = (const float*)d_in[0];
    const float* x2    = (const float*)d_in[1];
    const int*   flips = (const int*)d_in[2];
    float*       out   = (float*)d_out;

    const int grid = BCNT * 2 * CHALF * 4;   // 32 * 128 * 4 = 16384 tiles
    shuffle_aug_kernel<<<grid, 256, 0, stream>>>(x1, x2, flips, out);
}